// Round 5
// baseline (129.015 us; speedup 1.0000x reference)
//
#include <hip/hip_runtime.h>
#include <hip/hip_cooperative_groups.h>
#include <stdint.h>

namespace cg = cooperative_groups;

#define N_BOX 1024
#define NUM_CLASSES 80
#define MAX_OUT 100

// Compare-exchange, keep larger first if desc.
__device__ __forceinline__ void cas64(unsigned long long& a, unsigned long long& b, bool desc) {
    bool sw = desc ? (a < b) : (a > b);
    unsigned long long t = a;
    a = sw ? b : a;
    b = sw ? t : b;
}

// One cooperative kernel: per-class block does key build -> hybrid bitonic sort
// (registers + shfl_xor, only 3 LDS passes) -> greedy NMS with ON-THE-FLY IoU
// (no precomputed mask, no second kernel); grid.sync(); block 0 compacts.
__global__ __launch_bounds__(256) void nms_fused(const float* __restrict__ boxes,
                                                 const float* __restrict__ scores,
                                                 int* __restrict__ keptIdx,
                                                 int* __restrict__ counts,
                                                 int* __restrict__ out) {
    __shared__ float4 sbox[N_BOX];                // 16 KB  [y1,x1,y2,x2]
    __shared__ float sarea[N_BOX];                // 4 KB
    __shared__ unsigned long long keys[N_BOX];    // 8 KB
    __shared__ float4 kbox[MAX_OUT];              // kept boxes (for later windows)
    __shared__ float karea[MAX_OUT];

    cg::grid_group grid = cg::this_grid();
    const int c = blockIdx.x;
    const int tid = threadIdx.x;
    const int lane = tid & 63;

    for (int i = tid; i < N_BOX; i += 256) {
        float4 b = reinterpret_cast<const float4*>(boxes)[i];
        sbox[i] = b;
        sarea[i] = (b.z - b.x) * (b.w - b.y);
    }

    // Keys: (score_bits<<32) | (0xFFFFFFFF - idx); sort descending == stable argsort(-scores).
    const float* sc = scores + (size_t)c * N_BOX;
    float4 s4 = reinterpret_cast<const float4*>(sc)[tid];
    const int i0 = tid * 4;  // thread owns elements i0..i0+3 (contiguous)
    unsigned long long K[4];
    K[0] = ((unsigned long long)__float_as_uint(s4.x) << 32) | (unsigned long long)(0xFFFFFFFFu - (unsigned)(i0 + 0));
    K[1] = ((unsigned long long)__float_as_uint(s4.y) << 32) | (unsigned long long)(0xFFFFFFFFu - (unsigned)(i0 + 1));
    K[2] = ((unsigned long long)__float_as_uint(s4.z) << 32) | (unsigned long long)(0xFFFFFFFFu - (unsigned)(i0 + 2));
    K[3] = ((unsigned long long)__float_as_uint(s4.w) << 32) | (unsigned long long)(0xFFFFFFFFu - (unsigned)(i0 + 3));

    auto shfl_pass = [&](int j, bool d) {  // element-xor j>=4 -> lane-xor j/4 within wave
        int xl = j >> 2;
        bool mx = (d == ((lane & xl) == 0));
#pragma unroll
        for (int t = 0; t < 4; ++t) {
            unsigned long long p = __shfl_xor(K[t], xl, 64);
            K[t] = mx ? (K[t] >= p ? K[t] : p) : (K[t] <= p ? K[t] : p);
        }
    };
    auto thread_pass = [&](bool d) {  // j=2 then j=1, within this thread's 4 elements
        cas64(K[0], K[2], d); cas64(K[1], K[3], d);
        cas64(K[0], K[1], d); cas64(K[2], K[3], d);
    };
    auto lds_pass = [&](int j, bool d) {  // element-xor j>=256 -> cross-wave via LDS
        *reinterpret_cast<ulonglong2*>(&keys[i0])     = make_ulonglong2(K[0], K[1]);
        *reinterpret_cast<ulonglong2*>(&keys[i0 + 2]) = make_ulonglong2(K[2], K[3]);
        __syncthreads();
        int pb = i0 ^ j;
        ulonglong2 p01 = *reinterpret_cast<const ulonglong2*>(&keys[pb]);
        ulonglong2 p23 = *reinterpret_cast<const ulonglong2*>(&keys[pb + 2]);
        unsigned long long P[4] = {p01.x, p01.y, p23.x, p23.y};
        bool mx = (d == ((i0 & j) == 0));
#pragma unroll
        for (int t = 0; t < 4; ++t)
            K[t] = mx ? (K[t] >= P[t] ? K[t] : P[t]) : (K[t] <= P[t] ? K[t] : P[t]);
        __syncthreads();
    };

    // Bitonic network, descending overall (desc region when (i&k)==0).
    cas64(K[0], K[1], true);   // k=2: pair (0,1) desc
    cas64(K[2], K[3], false);  //      pair (2,3) asc
    { bool d = (tid & 1) == 0; thread_pass(d); }  // k=4
    for (int k = 8; k <= 256; k <<= 1) {          // k=8..256: all shfl + in-thread
        bool d = (tid & (k >> 2)) == 0;
        for (int j = k >> 1; j >= 4; j >>= 1) shfl_pass(j, d);
        thread_pass(d);
    }
    { bool d = (tid & 128) == 0;                  // k=512
      lds_pass(256, d);
      for (int j = 128; j >= 4; j >>= 1) shfl_pass(j, d);
      thread_pass(d); }
    {                                             // k=1024 (final, all desc)
      lds_pass(512, true); lds_pass(256, true);
      for (int j = 128; j >= 4; j >>= 1) shfl_pass(j, true);
      thread_pass(true); }
    // Publish sorted keys for the greedy wave.
    *reinterpret_cast<ulonglong2*>(&keys[i0])     = make_ulonglong2(K[0], K[1]);
    *reinterpret_cast<ulonglong2*>(&keys[i0 + 2]) = make_ulonglong2(K[2], K[3]);
    __syncthreads();

    // Greedy NMS on wave 0 (waves 1-3 wait at grid.sync; no barriers below).
    if (tid < 64) {
        int kept = 0;
        int* outc = keptIdx + c * MAX_OUT;
        for (int base = 0; base < N_BOX && kept < MAX_OUT; base += 64) {
            unsigned long long kk = keys[base + lane];
            unsigned int hi = (unsigned int)(kk >> 32);
            unsigned int o = 0xFFFFFFFFu - (unsigned int)kk;
            bool valid = hi > 0x3F000000u;           // score > 0.5f (nonneg floats)
            if (__ballot(valid) == 0ull) break;       // sorted: nothing left
            float4 mb = sbox[o];
            float ma = sarea[o];
            bool alive = valid;
            for (int j = 0; j < kept; ++j) {          // vs kept from earlier windows
                float4 kb = kbox[j];
                float ih = fminf(kb.z, mb.z) - fmaxf(kb.x, mb.x); ih = fmaxf(ih, 0.0f);
                float iw = fminf(kb.w, mb.w) - fmaxf(kb.y, mb.y); iw = fmaxf(iw, 0.0f);
                float inter = ih * iw;
                float uni = karea[j] + ma - inter;    // area_i + area_j - inter (ref order)
                alive = alive && !((inter / uni) > 0.5f);
            }
            unsigned long long m = __ballot(alive);
            while (m != 0ull && kept < MAX_OUT) {
                int f = __builtin_ctzll(m);           // next survivor in sorted order
                float fx = __shfl(mb.x, f), fy = __shfl(mb.y, f);
                float fz = __shfl(mb.z, f), fw = __shfl(mb.w, f);
                float fa = __shfl(ma, f);
                unsigned int of = (unsigned int)__shfl((int)o, f);
                float ih = fminf(fz, mb.z) - fmaxf(fx, mb.x); ih = fmaxf(ih, 0.0f);
                float iw = fminf(fw, mb.w) - fmaxf(fy, mb.y); iw = fmaxf(iw, 0.0f);
                float inter = ih * iw;
                float uni = fa + ma - inter;
                bool sup = (inter / uni) > 0.5f;      // self-IoU=1 removes f itself
                if (lane == 0) {
                    outc[kept] = (int)of;
                    kbox[kept] = make_float4(fx, fy, fz, fw);
                    karea[kept] = fa;
                }
                ++kept;
                m &= ~__ballot(sup);
            }
        }
        if (lane == 0) counts[c] = kept;
    }

    __threadfence();   // make counts/keptIdx device-visible before grid barrier
    grid.sync();

    // Phase 2: block 0 zeroes output (poisoned 0xAA), prefix-sums counts, scatters rows.
    if (blockIdx.x == 0) {
        int4* o4 = reinterpret_cast<int4*>(out);
        for (int i = tid; i < (NUM_CLASSES * MAX_OUT * 3) / 4; i += 256)
            o4[i] = make_int4(0, 0, 0, 0);
        __shared__ int offs[NUM_CLASSES + 1];
        if (tid == 0) {
            int s = 0;
            for (int c2 = 0; c2 < NUM_CLASSES; ++c2) { offs[c2] = s; s += counts[c2]; }
            offs[NUM_CLASSES] = s;
        }
        __syncthreads();
        for (int idx = tid; idx < NUM_CLASSES * MAX_OUT; idx += 256) {
            int c2 = idx / MAX_OUT;
            int r = idx - c2 * MAX_OUT;
            int o0 = offs[c2];
            if (r < offs[c2 + 1] - o0) {
                int o = o0 + r;
                out[o * 3 + 0] = 0;  // B == 1
                out[o * 3 + 1] = c2;
                out[o * 3 + 2] = keptIdx[c2 * MAX_OUT + r];
            }
        }
    }
}

extern "C" void kernel_launch(void* const* d_in, const int* in_sizes, int n_in,
                              void* d_out, int out_size, void* d_ws, size_t ws_size,
                              hipStream_t stream) {
    const float* boxes = (const float*)d_in[0];   // (1, 1024, 4) f32
    const float* scores = (const float*)d_in[1];  // (1, 80, 1024) f32
    int* out = (int*)d_out;                        // (8000, 3) int32

    int* keptIdx = (int*)d_ws;                     // 80*100 ints
    int* counts = keptIdx + NUM_CLASSES * MAX_OUT; // 80 ints

    void* args[] = {(void*)&boxes, (void*)&scores, (void*)&keptIdx, (void*)&counts, (void*)&out};
    hipLaunchCooperativeKernel((const void*)nms_fused, dim3(NUM_CLASSES), dim3(256),
                               args, 0, stream);
}

// Round 6
// 104.239 us; speedup vs baseline: 1.2377x; 1.2377x over previous
//
#include <hip/hip_runtime.h>
#include <stdint.h>

#define N_BOX 1024
#define NUM_CLASSES 80
#define MAX_OUT 100
#define MASK_WORDS (N_BOX / 64)  // 16 u64 words per row

// Kernel A: pairwise IoU > 0.5 bitmask over original box indices (shared by all classes).
__global__ __launch_bounds__(256) void iou_mask_kernel(const float* __restrict__ boxes,
                                                       unsigned long long* __restrict__ M) {
    __shared__ float4 sbox[N_BOX];   // 16 KB
    __shared__ float  sarea[N_BOX];  // 4 KB
    const int tid = threadIdx.x;
    for (int i = tid; i < N_BOX; i += 256) {
        float4 b = reinterpret_cast<const float4*>(boxes)[i];  // [y1,x1,y2,x2]
        sbox[i] = b;
        sarea[i] = (b.z - b.x) * (b.w - b.y);
    }
    __syncthreads();
    const int lane = tid & 63;
    const int wave = tid >> 6;
    const int row0 = blockIdx.x * 16;
    for (int r = 0; r < 16; ++r) {
        int row = row0 + r;
        float4 br = sbox[row];
        float ar = sarea[row];
#pragma unroll
        for (int k = 0; k < N_BOX / 256; ++k) {
            int col = k * 256 + wave * 64 + lane;
            float4 bc = sbox[col];
            // Match numpy op-for-op: min/max, clip at 0, inter/(ai+aj-inter), real divide.
            float ih = fminf(br.z, bc.z) - fmaxf(br.x, bc.x);
            ih = fmaxf(ih, 0.0f);
            float iw = fminf(br.w, bc.w) - fmaxf(br.y, bc.y);
            iw = fmaxf(iw, 0.0f);
            float inter = ih * iw;
            float uni = ar + sarea[col] - inter;
            unsigned long long m = __ballot((inter / uni) > 0.5f);
            if (lane == 0) M[(size_t)row * MASK_WORDS + k * 4 + wave] = m;
        }
    }
}

__device__ __forceinline__ void cas64(unsigned long long& a, unsigned long long& b, bool desc) {
    bool sw = desc ? (a < b) : (a > b);
    unsigned long long t = a;
    a = sw ? b : a;
    b = sw ? t : b;
}

// Kernel B: one block per class.
//  1. Stage the ENTIRE 128 KB M matrix into (dynamic) LDS — coalesced, independent,
//     one overlapped memory round trip (kills the per-window remote-L2 prefetch stalls).
//  2. Hybrid bitonic sort of (score_bits<<32 | ~idx) keys: registers + shfl_xor,
//     only 3 LDS passes / ~6 barriers (R5-verified network).
//  3. Wave-0 greedy with windowed ballot elimination, all row reads from LDS.
__global__ __launch_bounds__(256) void nms_class_kernel(const float* __restrict__ scores,
                                                        const unsigned long long* __restrict__ M,
                                                        int* __restrict__ keptIdx,
                                                        int* __restrict__ counts) {
    extern __shared__ unsigned long long Mlds[];   // 16384 u64 = 128 KB (dynamic)
    __shared__ unsigned long long keys[N_BOX];     // 8 KB
    const int c = blockIdx.x;
    const int tid = threadIdx.x;
    const int lane = tid & 63;

    // --- Stage M -> LDS (32 independent 16B loads per thread) ---
    {
        const ulonglong2* g = reinterpret_cast<const ulonglong2*>(M);
        ulonglong2* l = reinterpret_cast<ulonglong2*>(Mlds);
        for (int i = tid; i < N_BOX * MASK_WORDS / 2; i += 256) l[i] = g[i];
    }

    // --- Keys + hybrid register bitonic sort (descending) ---
    const float* sc = scores + (size_t)c * N_BOX;
    float4 s4 = reinterpret_cast<const float4*>(sc)[tid];
    const int i0 = tid * 4;
    unsigned long long K[4];
    K[0] = ((unsigned long long)__float_as_uint(s4.x) << 32) | (unsigned long long)(0xFFFFFFFFu - (unsigned)(i0 + 0));
    K[1] = ((unsigned long long)__float_as_uint(s4.y) << 32) | (unsigned long long)(0xFFFFFFFFu - (unsigned)(i0 + 1));
    K[2] = ((unsigned long long)__float_as_uint(s4.z) << 32) | (unsigned long long)(0xFFFFFFFFu - (unsigned)(i0 + 2));
    K[3] = ((unsigned long long)__float_as_uint(s4.w) << 32) | (unsigned long long)(0xFFFFFFFFu - (unsigned)(i0 + 3));

    auto shfl_pass = [&](int j, bool d) {  // element-xor j>=4 -> lane-xor j/4 within wave
        int xl = j >> 2;
        bool mx = (d == ((lane & xl) == 0));
#pragma unroll
        for (int t = 0; t < 4; ++t) {
            unsigned long long p = __shfl_xor(K[t], xl, 64);
            K[t] = mx ? (K[t] >= p ? K[t] : p) : (K[t] <= p ? K[t] : p);
        }
    };
    auto thread_pass = [&](bool d) {
        cas64(K[0], K[2], d); cas64(K[1], K[3], d);
        cas64(K[0], K[1], d); cas64(K[2], K[3], d);
    };
    auto lds_pass = [&](int j, bool d) {  // cross-wave via LDS
        *reinterpret_cast<ulonglong2*>(&keys[i0])     = make_ulonglong2(K[0], K[1]);
        *reinterpret_cast<ulonglong2*>(&keys[i0 + 2]) = make_ulonglong2(K[2], K[3]);
        __syncthreads();
        int pb = i0 ^ j;
        ulonglong2 p01 = *reinterpret_cast<const ulonglong2*>(&keys[pb]);
        ulonglong2 p23 = *reinterpret_cast<const ulonglong2*>(&keys[pb + 2]);
        unsigned long long P[4] = {p01.x, p01.y, p23.x, p23.y};
        bool mx = (d == ((i0 & j) == 0));
#pragma unroll
        for (int t = 0; t < 4; ++t)
            K[t] = mx ? (K[t] >= P[t] ? K[t] : P[t]) : (K[t] <= P[t] ? K[t] : P[t]);
        __syncthreads();
    };

    cas64(K[0], K[1], true);   // k=2
    cas64(K[2], K[3], false);
    { bool d = (tid & 1) == 0; thread_pass(d); }  // k=4
    for (int k = 8; k <= 256; k <<= 1) {
        bool d = (tid & (k >> 2)) == 0;
        for (int j = k >> 1; j >= 4; j >>= 1) shfl_pass(j, d);
        thread_pass(d);
    }
    { bool d = (tid & 128) == 0;  // k=512
      lds_pass(256, d);
      for (int j = 128; j >= 4; j >>= 1) shfl_pass(j, d);
      thread_pass(d); }
    {                             // k=1024 (final, all desc)
      lds_pass(512, true); lds_pass(256, true);
      for (int j = 128; j >= 4; j >>= 1) shfl_pass(j, true);
      thread_pass(true); }
    *reinterpret_cast<ulonglong2*>(&keys[i0])     = make_ulonglong2(K[0], K[1]);
    *reinterpret_cast<ulonglong2*>(&keys[i0 + 2]) = make_ulonglong2(K[2], K[3]);
    __syncthreads();  // keys published AND all M staging writes complete

    // --- Greedy NMS on wave 0 (waves 1-3 exit; no barriers below) ---
    if (tid < 64) {
        unsigned long long S = 0ull;  // lane w<16 holds suppression word w (orig idx space)
        int kept = 0;
        int* outc = keptIdx + c * MAX_OUT;
        for (int base = 0; base < N_BOX && kept < MAX_OUT; base += 64) {
            unsigned long long kk = keys[base + lane];
            unsigned int hi = (unsigned int)(kk >> 32);
            unsigned int o = 0xFFFFFFFFu - (unsigned int)kk;
            bool valid = hi > 0x3F000000u;           // score > 0.5f (nonneg floats)
            if (__ballot(valid) == 0ull) break;      // sorted: nothing left
            unsigned int w = o >> 6;
            unsigned long long bit = 1ull << (o & 63);
            unsigned long long Sw = __shfl(S, (int)w);
            bool alive = valid && ((Sw & bit) == 0ull);
            unsigned long long m = __ballot(alive);
            while (m != 0ull && kept < MAX_OUT) {
                int f = __builtin_ctzll(m);
                unsigned int of = (unsigned int)__builtin_amdgcn_readlane((int)o, f);
                const unsigned long long* rowp = Mlds + (size_t)of * MASK_WORDS;
                unsigned long long rw = rowp[w];            // my candidate's word
                unsigned long long rs = rowp[lane & 15];    // for S update
                if (lane < MASK_WORDS) S |= rs;
                if (lane == 0) outc[kept] = (int)of;
                ++kept;
                m &= ~__ballot((rw & bit) != 0ull);  // drop all f suppresses (incl. f)
            }
        }
        if (lane == 0) counts[c] = kept;
    }
}

// Kernel C: zero output, exclusive prefix over counts, scatter (0, c, idx) packed rows.
__global__ __launch_bounds__(256) void compact_kernel(const int* __restrict__ keptIdx,
                                                      const int* __restrict__ counts,
                                                      int* __restrict__ out) {
    int4* o4 = reinterpret_cast<int4*>(out);
    for (int i = threadIdx.x; i < (NUM_CLASSES * MAX_OUT * 3) / 4; i += 256)
        o4[i] = make_int4(0, 0, 0, 0);
    __shared__ int offs[NUM_CLASSES + 1];
    if (threadIdx.x == 0) {
        int s = 0;
        for (int c = 0; c < NUM_CLASSES; ++c) { offs[c] = s; s += counts[c]; }
        offs[NUM_CLASSES] = s;
    }
    __syncthreads();
    for (int idx = threadIdx.x; idx < NUM_CLASSES * MAX_OUT; idx += 256) {
        int c = idx / MAX_OUT;
        int r = idx - c * MAX_OUT;
        int o0 = offs[c];
        if (r < offs[c + 1] - o0) {
            int o = o0 + r;
            out[o * 3 + 0] = 0;  // B == 1
            out[o * 3 + 1] = c;
            out[o * 3 + 2] = keptIdx[c * MAX_OUT + r];
        }
    }
}

extern "C" void kernel_launch(void* const* d_in, const int* in_sizes, int n_in,
                              void* d_out, int out_size, void* d_ws, size_t ws_size,
                              hipStream_t stream) {
    const float* boxes = (const float*)d_in[0];   // (1, 1024, 4) f32
    const float* scores = (const float*)d_in[1];  // (1, 80, 1024) f32
    int* out = (int*)d_out;                        // (8000, 3) int32

    unsigned long long* M = (unsigned long long*)d_ws;                    // 128 KB
    int* keptIdx = (int*)((char*)d_ws + (size_t)N_BOX * MASK_WORDS * 8);  // 80*100 ints
    int* counts = keptIdx + NUM_CLASSES * MAX_OUT;                        // 80 ints

    const int dyn_lds = N_BOX * MASK_WORDS * 8;  // 128 KB dynamic (+8 KB static keys)
    (void)hipFuncSetAttribute((const void*)nms_class_kernel,
                              hipFuncAttributeMaxDynamicSharedMemorySize, dyn_lds);

    iou_mask_kernel<<<64, 256, 0, stream>>>(boxes, M);
    nms_class_kernel<<<NUM_CLASSES, 256, dyn_lds, stream>>>(scores, M, keptIdx, counts);
    compact_kernel<<<1, 256, 0, stream>>>(keptIdx, counts, out);
}

// Round 7
// 103.136 us; speedup vs baseline: 1.2509x; 1.0107x over previous
//
#include <hip/hip_runtime.h>
#include <stdint.h>

#define N_BOX 1024
#define NUM_CLASSES 80
#define MAX_OUT 100

__device__ __forceinline__ void cas64(unsigned long long& a, unsigned long long& b, bool desc) {
    bool sw = desc ? (a < b) : (a > b);
    unsigned long long t = a;
    a = sw ? b : a;
    b = sw ? t : b;
}

// One block per class. No precomputed IoU mask, no cooperative launch.
//  1. Stage boxes+areas into LDS (16+4 KB, coalesced).
//  2. Hybrid bitonic sort of (score_bits<<32 | ~idx) keys: registers + shfl_xor,
//     3 LDS passes / ~6 barriers (verified R5/R6).
//  3. Wave-0 greedy with ON-THE-FLY IoU (verified R5): per 64-window, test lanes'
//     candidates vs kept list in LDS, then ballot-eliminate within the window;
//     per kept box: 6 shfl broadcast + ~15 VALU IoU + 1 ballot (~120 cyc).
__global__ __launch_bounds__(256) void nms_class_kernel(const float* __restrict__ boxes,
                                                        const float* __restrict__ scores,
                                                        int* __restrict__ keptIdx,
                                                        int* __restrict__ counts) {
    __shared__ float4 sbox[N_BOX];              // 16 KB  [y1,x1,y2,x2]
    __shared__ float sarea[N_BOX];              // 4 KB
    __shared__ unsigned long long keys[N_BOX];  // 8 KB
    __shared__ float4 kbox[MAX_OUT];            // kept boxes
    __shared__ float karea[MAX_OUT];
    const int c = blockIdx.x;
    const int tid = threadIdx.x;
    const int lane = tid & 63;

    for (int i = tid; i < N_BOX; i += 256) {
        float4 b = reinterpret_cast<const float4*>(boxes)[i];
        sbox[i] = b;
        sarea[i] = (b.z - b.x) * (b.w - b.y);
    }

    // Keys: (score_bits<<32) | (0xFFFFFFFF - idx); descending sort == stable argsort(-scores).
    const float* sc = scores + (size_t)c * N_BOX;
    float4 s4 = reinterpret_cast<const float4*>(sc)[tid];
    const int i0 = tid * 4;
    unsigned long long K[4];
    K[0] = ((unsigned long long)__float_as_uint(s4.x) << 32) | (unsigned long long)(0xFFFFFFFFu - (unsigned)(i0 + 0));
    K[1] = ((unsigned long long)__float_as_uint(s4.y) << 32) | (unsigned long long)(0xFFFFFFFFu - (unsigned)(i0 + 1));
    K[2] = ((unsigned long long)__float_as_uint(s4.z) << 32) | (unsigned long long)(0xFFFFFFFFu - (unsigned)(i0 + 2));
    K[3] = ((unsigned long long)__float_as_uint(s4.w) << 32) | (unsigned long long)(0xFFFFFFFFu - (unsigned)(i0 + 3));

    auto shfl_pass = [&](int j, bool d) {  // element-xor j>=4 -> lane-xor j/4 within wave
        int xl = j >> 2;
        bool mx = (d == ((lane & xl) == 0));
#pragma unroll
        for (int t = 0; t < 4; ++t) {
            unsigned long long p = __shfl_xor(K[t], xl, 64);
            K[t] = mx ? (K[t] >= p ? K[t] : p) : (K[t] <= p ? K[t] : p);
        }
    };
    auto thread_pass = [&](bool d) {
        cas64(K[0], K[2], d); cas64(K[1], K[3], d);
        cas64(K[0], K[1], d); cas64(K[2], K[3], d);
    };
    auto lds_pass = [&](int j, bool d) {  // cross-wave via LDS
        *reinterpret_cast<ulonglong2*>(&keys[i0])     = make_ulonglong2(K[0], K[1]);
        *reinterpret_cast<ulonglong2*>(&keys[i0 + 2]) = make_ulonglong2(K[2], K[3]);
        __syncthreads();
        int pb = i0 ^ j;
        ulonglong2 p01 = *reinterpret_cast<const ulonglong2*>(&keys[pb]);
        ulonglong2 p23 = *reinterpret_cast<const ulonglong2*>(&keys[pb + 2]);
        unsigned long long P[4] = {p01.x, p01.y, p23.x, p23.y};
        bool mx = (d == ((i0 & j) == 0));
#pragma unroll
        for (int t = 0; t < 4; ++t)
            K[t] = mx ? (K[t] >= P[t] ? K[t] : P[t]) : (K[t] <= P[t] ? K[t] : P[t]);
        __syncthreads();
    };

    cas64(K[0], K[1], true);   // k=2
    cas64(K[2], K[3], false);
    { bool d = (tid & 1) == 0; thread_pass(d); }  // k=4
    for (int k = 8; k <= 256; k <<= 1) {
        bool d = (tid & (k >> 2)) == 0;
        for (int j = k >> 1; j >= 4; j >>= 1) shfl_pass(j, d);
        thread_pass(d);
    }
    { bool d = (tid & 128) == 0;  // k=512
      lds_pass(256, d);
      for (int j = 128; j >= 4; j >>= 1) shfl_pass(j, d);
      thread_pass(d); }
    {                             // k=1024 (final, all desc)
      lds_pass(512, true); lds_pass(256, true);
      for (int j = 128; j >= 4; j >>= 1) shfl_pass(j, true);
      thread_pass(true); }
    *reinterpret_cast<ulonglong2*>(&keys[i0])     = make_ulonglong2(K[0], K[1]);
    *reinterpret_cast<ulonglong2*>(&keys[i0 + 2]) = make_ulonglong2(K[2], K[3]);
    __syncthreads();  // keys published; sbox/sarea staging also complete

    // Greedy NMS on wave 0 (waves 1-3 exit; no barriers below).
    if (tid < 64) {
        int kept = 0;
        int* outc = keptIdx + c * MAX_OUT;
        for (int base = 0; base < N_BOX && kept < MAX_OUT; base += 64) {
            unsigned long long kk = keys[base + lane];
            unsigned int hi = (unsigned int)(kk >> 32);
            unsigned int o = 0xFFFFFFFFu - (unsigned int)kk;
            bool valid = hi > 0x3F000000u;           // score > 0.5f (nonneg floats)
            if (__ballot(valid) == 0ull) break;      // sorted: nothing left
            float4 mb = sbox[o];
            float ma = sarea[o];
            bool alive = valid;
            for (int j = 0; j < kept; ++j) {         // vs kept from earlier windows
                float4 kb = kbox[j];
                float ih = fminf(kb.z, mb.z) - fmaxf(kb.x, mb.x); ih = fmaxf(ih, 0.0f);
                float iw = fminf(kb.w, mb.w) - fmaxf(kb.y, mb.y); iw = fmaxf(iw, 0.0f);
                float inter = ih * iw;
                float uni = karea[j] + ma - inter;   // ref op order
                alive = alive && !((inter / uni) > 0.5f);
            }
            unsigned long long m = __ballot(alive);
            while (m != 0ull && kept < MAX_OUT) {
                int f = __builtin_ctzll(m);          // next survivor in sorted order
                float fx = __shfl(mb.x, f), fy = __shfl(mb.y, f);
                float fz = __shfl(mb.z, f), fw = __shfl(mb.w, f);
                float fa = __shfl(ma, f);
                unsigned int of = (unsigned int)__shfl((int)o, f);
                float ih = fminf(fz, mb.z) - fmaxf(fx, mb.x); ih = fmaxf(ih, 0.0f);
                float iw = fminf(fw, mb.w) - fmaxf(fy, mb.y); iw = fmaxf(iw, 0.0f);
                float inter = ih * iw;
                float uni = fa + ma - inter;
                bool sup = (inter / uni) > 0.5f;     // self-IoU=1 removes f itself
                if (lane == 0) {
                    outc[kept] = (int)of;
                    kbox[kept] = make_float4(fx, fy, fz, fw);
                    karea[kept] = fa;
                }
                ++kept;
                m &= ~__ballot(sup);
            }
        }
        if (lane == 0) counts[c] = kept;
    }
}

// Kernel C: zero output, exclusive prefix over counts, scatter (0, c, idx) packed rows.
__global__ __launch_bounds__(256) void compact_kernel(const int* __restrict__ keptIdx,
                                                      const int* __restrict__ counts,
                                                      int* __restrict__ out) {
    int4* o4 = reinterpret_cast<int4*>(out);
    for (int i = threadIdx.x; i < (NUM_CLASSES * MAX_OUT * 3) / 4; i += 256)
        o4[i] = make_int4(0, 0, 0, 0);
    __shared__ int offs[NUM_CLASSES + 1];
    if (threadIdx.x == 0) {
        int s = 0;
        for (int c = 0; c < NUM_CLASSES; ++c) { offs[c] = s; s += counts[c]; }
        offs[NUM_CLASSES] = s;
    }
    __syncthreads();
    for (int idx = threadIdx.x; idx < NUM_CLASSES * MAX_OUT; idx += 256) {
        int c = idx / MAX_OUT;
        int r = idx - c * MAX_OUT;
        int o0 = offs[c];
        if (r < offs[c + 1] - o0) {
            int o = o0 + r;
            out[o * 3 + 0] = 0;  // B == 1
            out[o * 3 + 1] = c;
            out[o * 3 + 2] = keptIdx[c * MAX_OUT + r];
        }
    }
}

extern "C" void kernel_launch(void* const* d_in, const int* in_sizes, int n_in,
                              void* d_out, int out_size, void* d_ws, size_t ws_size,
                              hipStream_t stream) {
    const float* boxes = (const float*)d_in[0];   // (1, 1024, 4) f32
    const float* scores = (const float*)d_in[1];  // (1, 80, 1024) f32
    int* out = (int*)d_out;                        // (8000, 3) int32

    int* keptIdx = (int*)d_ws;                     // 80*100 ints
    int* counts = keptIdx + NUM_CLASSES * MAX_OUT; // 80 ints

    nms_class_kernel<<<NUM_CLASSES, 256, 0, stream>>>(boxes, scores, keptIdx, counts);
    compact_kernel<<<1, 256, 0, stream>>>(keptIdx, counts, out);
}

// Round 8
// 100.836 us; speedup vs baseline: 1.2795x; 1.0228x over previous
//
#include <hip/hip_runtime.h>
#include <stdint.h>

#define N_BOX 1024
#define NUM_CLASSES 80
#define MAX_OUT 100
#define KEPT_STRIDE 128  // ints per class (512 B) — no cross-XCD false sharing

__device__ __forceinline__ void cas64(unsigned long long& a, unsigned long long& b, bool desc) {
    bool sw = desc ? (a < b) : (a > b);
    unsigned long long t = a;
    a = sw ? b : a;
    b = sw ? t : b;
}

// Single fused dispatch, 80 blocks (one class each), no cooperative launch.
//  - sort: hybrid register/shfl bitonic (verified R5-R7), all 4 waves
//  - greedy: wave 0, on-the-fly IoU (verified R5/R7)
//  - each block release-stores counts[c] (agent scope) after lane-0 keptIdx writes
//  - block 0: waves 1-2 spin-acquire on counts (poison 0xAAAAAAAA>100 = not ready),
//    waves 2-3 zero d_out meanwhile; then barrier, LDS prefix scan, scatter.
__global__ __launch_bounds__(256) void nms_fused(const float* __restrict__ boxes,
                                                 const float* __restrict__ scores,
                                                 int* __restrict__ keptIdx,
                                                 unsigned int* __restrict__ counts,
                                                 int* __restrict__ out) {
    __shared__ float4 sbox[N_BOX];              // 16 KB  [y1,x1,y2,x2]
    __shared__ float sarea[N_BOX];              // 4 KB
    __shared__ unsigned long long keys[N_BOX];  // 8 KB
    __shared__ float4 kbox[MAX_OUT];            // kept boxes
    __shared__ float karea[MAX_OUT];
    __shared__ int scnt[NUM_CLASSES];           // block 0: gathered counts -> inclusive scan
    const int c = blockIdx.x;
    const int tid = threadIdx.x;
    const int lane = tid & 63;

    for (int i = tid; i < N_BOX; i += 256) {
        float4 b = reinterpret_cast<const float4*>(boxes)[i];
        sbox[i] = b;
        sarea[i] = (b.z - b.x) * (b.w - b.y);
    }

    // Keys: (score_bits<<32) | (0xFFFFFFFF - idx); descending == stable argsort(-scores).
    const float* sc = scores + (size_t)c * N_BOX;
    float4 s4 = reinterpret_cast<const float4*>(sc)[tid];
    const int i0 = tid * 4;
    unsigned long long K[4];
    K[0] = ((unsigned long long)__float_as_uint(s4.x) << 32) | (unsigned long long)(0xFFFFFFFFu - (unsigned)(i0 + 0));
    K[1] = ((unsigned long long)__float_as_uint(s4.y) << 32) | (unsigned long long)(0xFFFFFFFFu - (unsigned)(i0 + 1));
    K[2] = ((unsigned long long)__float_as_uint(s4.z) << 32) | (unsigned long long)(0xFFFFFFFFu - (unsigned)(i0 + 2));
    K[3] = ((unsigned long long)__float_as_uint(s4.w) << 32) | (unsigned long long)(0xFFFFFFFFu - (unsigned)(i0 + 3));

    auto shfl_pass = [&](int j, bool d) {  // element-xor j>=4 -> lane-xor j/4 within wave
        int xl = j >> 2;
        bool mx = (d == ((lane & xl) == 0));
#pragma unroll
        for (int t = 0; t < 4; ++t) {
            unsigned long long p = __shfl_xor(K[t], xl, 64);
            K[t] = mx ? (K[t] >= p ? K[t] : p) : (K[t] <= p ? K[t] : p);
        }
    };
    auto thread_pass = [&](bool d) {
        cas64(K[0], K[2], d); cas64(K[1], K[3], d);
        cas64(K[0], K[1], d); cas64(K[2], K[3], d);
    };
    auto lds_pass = [&](int j, bool d) {  // cross-wave via LDS
        *reinterpret_cast<ulonglong2*>(&keys[i0])     = make_ulonglong2(K[0], K[1]);
        *reinterpret_cast<ulonglong2*>(&keys[i0 + 2]) = make_ulonglong2(K[2], K[3]);
        __syncthreads();
        int pb = i0 ^ j;
        ulonglong2 p01 = *reinterpret_cast<const ulonglong2*>(&keys[pb]);
        ulonglong2 p23 = *reinterpret_cast<const ulonglong2*>(&keys[pb + 2]);
        unsigned long long P[4] = {p01.x, p01.y, p23.x, p23.y};
        bool mx = (d == ((i0 & j) == 0));
#pragma unroll
        for (int t = 0; t < 4; ++t)
            K[t] = mx ? (K[t] >= P[t] ? K[t] : P[t]) : (K[t] <= P[t] ? K[t] : P[t]);
        __syncthreads();
    };

    cas64(K[0], K[1], true);   // k=2
    cas64(K[2], K[3], false);
    { bool d = (tid & 1) == 0; thread_pass(d); }  // k=4
    for (int k = 8; k <= 256; k <<= 1) {
        bool d = (tid & (k >> 2)) == 0;
        for (int j = k >> 1; j >= 4; j >>= 1) shfl_pass(j, d);
        thread_pass(d);
    }
    { bool d = (tid & 128) == 0;  // k=512
      lds_pass(256, d);
      for (int j = 128; j >= 4; j >>= 1) shfl_pass(j, d);
      thread_pass(d); }
    {                             // k=1024 (final, all desc)
      lds_pass(512, true); lds_pass(256, true);
      for (int j = 128; j >= 4; j >>= 1) shfl_pass(j, true);
      thread_pass(true); }
    *reinterpret_cast<ulonglong2*>(&keys[i0])     = make_ulonglong2(K[0], K[1]);
    *reinterpret_cast<ulonglong2*>(&keys[i0 + 2]) = make_ulonglong2(K[2], K[3]);
    __syncthreads();  // keys published; sbox/sarea staging complete

    // --- Greedy NMS on wave 0 (verified R5/R7) ---
    if (tid < 64) {
        int kept = 0;
        int* outc = keptIdx + c * KEPT_STRIDE;
        for (int base = 0; base < N_BOX && kept < MAX_OUT; base += 64) {
            unsigned long long kk = keys[base + lane];
            unsigned int hi = (unsigned int)(kk >> 32);
            unsigned int o = 0xFFFFFFFFu - (unsigned int)kk;
            bool valid = hi > 0x3F000000u;           // score > 0.5f (nonneg floats)
            if (__ballot(valid) == 0ull) break;      // sorted: nothing left
            float4 mb = sbox[o];
            float ma = sarea[o];
            bool alive = valid;
            for (int j = 0; j < kept; ++j) {         // vs kept from earlier windows
                float4 kb = kbox[j];
                float ih = fminf(kb.z, mb.z) - fmaxf(kb.x, mb.x); ih = fmaxf(ih, 0.0f);
                float iw = fminf(kb.w, mb.w) - fmaxf(kb.y, mb.y); iw = fmaxf(iw, 0.0f);
                float inter = ih * iw;
                float uni = karea[j] + ma - inter;   // ref op order
                alive = alive && !((inter / uni) > 0.5f);
            }
            unsigned long long m = __ballot(alive);
            while (m != 0ull && kept < MAX_OUT) {
                int f = __builtin_ctzll(m);          // next survivor in sorted order
                float fx = __shfl(mb.x, f), fy = __shfl(mb.y, f);
                float fz = __shfl(mb.z, f), fw = __shfl(mb.w, f);
                float fa = __shfl(ma, f);
                unsigned int of = (unsigned int)__shfl((int)o, f);
                float ih = fminf(fz, mb.z) - fmaxf(fx, mb.x); ih = fmaxf(ih, 0.0f);
                float iw = fminf(fw, mb.w) - fmaxf(fy, mb.y); iw = fmaxf(iw, 0.0f);
                float inter = ih * iw;
                float uni = fa + ma - inter;
                bool sup = (inter / uni) > 0.5f;     // self-IoU=1 removes f itself
                if (lane == 0) {
                    outc[kept] = (int)of;
                    kbox[kept] = make_float4(fx, fy, fz, fw);
                    karea[kept] = fa;
                }
                ++kept;
                m &= ~__ballot(sup);
            }
        }
        // Release: makes lane 0's keptIdx writes agent-visible before count publishes.
        if (lane == 0)
            __hip_atomic_store(&counts[c], (unsigned int)kept,
                               __ATOMIC_RELEASE, __HIP_MEMORY_SCOPE_AGENT);
    }

    if (c != 0) return;  // blocks 1..79 done (waves 1-3 already fell through to here)

    // --- Block 0 epilogue ---
    // waves: 0 = greedy (above); tids 64..143 spin-gather counts; tids 144..255 zero out.
    if (tid >= 64 && tid < 64 + NUM_CLASSES) {
        int j = tid - 64;
        unsigned int v;
        do {
            v = __hip_atomic_load(&counts[j], __ATOMIC_ACQUIRE, __HIP_MEMORY_SCOPE_AGENT);
        } while (v > (unsigned)MAX_OUT);   // 0xAAAAAAAA poison = not ready
        scnt[j] = (int)v;
    } else if (tid >= 144) {
        int4* o4 = reinterpret_cast<int4*>(out);
        for (int i = tid - 144; i < (NUM_CLASSES * MAX_OUT * 3) / 4; i += 112)
            o4[i] = make_int4(0, 0, 0, 0);
    }
    __syncthreads();  // greedy done, all counts gathered, out zeroed

    // Inclusive Hillis-Steele scan over 80 counts in LDS.
    for (int d = 1; d < NUM_CLASSES; d <<= 1) {
        int v = 0;
        if (tid < NUM_CLASSES) {
            v = scnt[tid];
            if (tid >= d) v += scnt[tid - d];
        }
        __syncthreads();
        if (tid < NUM_CLASSES) scnt[tid] = v;
        __syncthreads();
    }

    // Scatter rows (0, c, idx) packed by (class, rank).
    for (int idx = tid; idx < NUM_CLASSES * MAX_OUT; idx += 256) {
        int c2 = idx / MAX_OUT;
        int r = idx - c2 * MAX_OUT;
        int excl = (c2 == 0) ? 0 : scnt[c2 - 1];
        if (r < scnt[c2] - excl) {
            int o = excl + r;
            out[o * 3 + 0] = 0;  // B == 1
            out[o * 3 + 1] = c2;
            out[o * 3 + 2] = keptIdx[c2 * KEPT_STRIDE + r];
        }
    }
}

extern "C" void kernel_launch(void* const* d_in, const int* in_sizes, int n_in,
                              void* d_out, int out_size, void* d_ws, size_t ws_size,
                              hipStream_t stream) {
    const float* boxes = (const float*)d_in[0];   // (1, 1024, 4) f32
    const float* scores = (const float*)d_in[1];  // (1, 80, 1024) f32
    int* out = (int*)d_out;                        // (8000, 3) int32

    int* keptIdx = (int*)d_ws;                                    // 80*128 ints (512B/class)
    unsigned int* counts = (unsigned int*)(keptIdx + NUM_CLASSES * KEPT_STRIDE);

    nms_fused<<<NUM_CLASSES, 256, 0, stream>>>(boxes, scores, keptIdx, counts, out);
}